// Round 8
// baseline (443.077 us; speedup 1.0000x reference)
//
#include <hip/hip_runtime.h>
#include <math.h>
#include <stdint.h>

#define CDIM 128
#define NTOT 4096

typedef _Float16 f16x8 __attribute__((ext_vector_type(8)));  // 8 fp16 (4 VGPRs)
typedef float floatx4 __attribute__((ext_vector_type(4)));   // MFMA accumulator

static __device__ __forceinline__ floatx4 mfma16(f16x8 a, f16x8 b, floatx4 c) {
    return __builtin_amdgcn_mfma_f32_16x16x32_f16(a, b, c, 0, 0, 0);
}
static __device__ __forceinline__ unsigned short f2h(float f) {
    _Float16 h = (_Float16)f;
    return __builtin_bit_cast(unsigned short, h);
}

// ---------------------------------------------------------------------------
// Fused q/k/v projection, MFMA. x: [4][128][4096] fp32.
// Outputs fp16: qo, ko: [b][n][c]; vo: [b][c][n].
// grid (64 n-tiles, 4 batches, 2 o-halves), 256 threads / 4 waves.
// ---------------------------------------------------------------------------
__global__ __launch_bounds__(256) void qkv_proj_kernel(
    const float* __restrict__ x,
    const float* __restrict__ Wq, const float* __restrict__ bq,
    const float* __restrict__ Wk, const float* __restrict__ bk,
    const float* __restrict__ Wv, const float* __restrict__ bv,
    unsigned short* __restrict__ qo, unsigned short* __restrict__ ko,
    unsigned short* __restrict__ vo)
{
    __shared__ __align__(16) unsigned short Xs[64][136];   // [n][c] fp16
    __shared__ __align__(16) unsigned short Ws[64][136];   // [o-half][c] fp16

    const int t = threadIdx.x, b = blockIdx.y, n0 = blockIdx.x * 64;
    const int zo = blockIdx.z * 64;
    const int w = t >> 6, quad = (t >> 4) & 3, l15 = t & 15;

    // stage x tile with transpose-on-store: thread covers 4n x 8c
    {
        const int n = (t & 15) * 4;
        const int c = (t >> 4) * 8;
        float4 xr[8];
        #pragma unroll
        for (int j = 0; j < 8; ++j)
            xr[j] = *(const float4*)&x[((size_t)b * CDIM + c + j) * NTOT + n0 + n];
        #pragma unroll
        for (int k = 0; k < 4; ++k) {
            ushort4 ulo, uhi;
            ulo.x = f2h(((const float*)&xr[0])[k]);
            ulo.y = f2h(((const float*)&xr[1])[k]);
            ulo.z = f2h(((const float*)&xr[2])[k]);
            ulo.w = f2h(((const float*)&xr[3])[k]);
            uhi.x = f2h(((const float*)&xr[4])[k]);
            uhi.y = f2h(((const float*)&xr[5])[k]);
            uhi.z = f2h(((const float*)&xr[6])[k]);
            uhi.w = f2h(((const float*)&xr[7])[k]);
            *(ushort4*)&Xs[n + k][c]     = ulo;
            *(ushort4*)&Xs[n + k][c + 4] = uhi;
        }
    }

    f16x8 xf[4];
    for (int s = 0; s < 3; ++s) {
        const float* W    = (s == 0) ? Wq : (s == 1) ? Wk : Wv;
        const float* bias = (s == 0) ? bq : (s == 1) ? bk : bv;
        if (s) __syncthreads();   // previous Ws readers done
        {
            int o = t >> 2, ch = (t & 3) * 32;
            #pragma unroll
            for (int i = 0; i < 8; ++i) {
                float4 f4 = *(const float4*)&W[(size_t)(zo + o) * CDIM + ch + i * 4];
                ushort4 u = { f2h(f4.x), f2h(f4.y), f2h(f4.z), f2h(f4.w) };
                *(ushort4*)&Ws[o][ch + i * 4] = u;
            }
        }
        __syncthreads();          // Ws (and on s==0, Xs) ready
        if (s == 0) {
            #pragma unroll
            for (int f = 0; f < 4; ++f)
                xf[f] = *(const f16x8*)&Xs[w * 16 + l15][f * 32 + quad * 8];
        }

        if (s < 2) {   // q, k: C[o][n], A = W, B = X
            unsigned short* dst = (s == 0) ? qo : ko;
            #pragma unroll
            for (int ot = 0; ot < 4; ++ot) {
                floatx4 acc = (floatx4){0.f, 0.f, 0.f, 0.f};
                #pragma unroll
                for (int f = 0; f < 4; ++f) {
                    f16x8 aW = *(const f16x8*)&Ws[ot * 16 + l15][f * 32 + quad * 8];
                    acc = mfma16(aW, xf[f], acc);
                }
                const int ob = zo + ot * 16 + quad * 4;
                ushort4 u;
                u.x = f2h(acc[0] + bias[ob + 0]);
                u.y = f2h(acc[1] + bias[ob + 1]);
                u.z = f2h(acc[2] + bias[ob + 2]);
                u.w = f2h(acc[3] + bias[ob + 3]);
                *(ushort4*)&dst[((size_t)b * NTOT + n0 + w * 16 + l15) * CDIM + ob] = u;
            }
        } else {       // v: C'[n][o], A = X, B = W
            #pragma unroll
            for (int ot = 0; ot < 4; ++ot) {
                floatx4 acc = (floatx4){0.f, 0.f, 0.f, 0.f};
                #pragma unroll
                for (int f = 0; f < 4; ++f) {
                    f16x8 bW = *(const f16x8*)&Ws[ot * 16 + l15][f * 32 + quad * 8];
                    acc = mfma16(xf[f], bW, acc);
                }
                const int o = zo + ot * 16 + l15;
                const float bv_ = bias[o];
                ushort4 u;
                u.x = f2h(acc[0] + bv_); u.y = f2h(acc[1] + bv_);
                u.z = f2h(acc[2] + bv_); u.w = f2h(acc[3] + bv_);
                *(ushort4*)&vo[((size_t)b * CDIM + o) * NTOT + n0 + w * 16 + quad * 4] = u;
            }
        }
    }
}

// ---------------------------------------------------------------------------
// Flash attention. q,k: [b][n][128] fp16; v: [b][128][n] fp16;
// ao: [b][n][128] fp16. grid (128 q-tiles, 4 batches), 128 threads / 2 waves.
// BQ=32 (wave w owns queries i = w*16+l15), KT=128, 32 iterations.
// 512 blocks, LDS 68 KB -> 2 co-resident blocks/CU with independent barriers.
// NO register prefetch (R6/R7's scratch-spill bug), no split-K.
// Ps overlaid on Ks rows 0..31 after barrier C (S-phase Ks reads done).
// ---------------------------------------------------------------------------
__global__ __launch_bounds__(128) void attn_kernel(
    const unsigned short* __restrict__ qg,
    const unsigned short* __restrict__ kg,
    const unsigned short* __restrict__ vg,
    unsigned short* __restrict__ aog)
{
    __shared__ __align__(16) unsigned short Ks[128 * 136];   // [j][c] 34 KB (rows 0..31 reused as Ps)
    __shared__ __align__(16) unsigned short Vs[128 * 136];   // [d][j] 34 KB

    const int t = threadIdx.x;
    const int w = t >> 6, quad = (t >> 4) & 3, l15 = t & 15;
    const int b = blockIdx.y;
    const int i0 = blockIdx.x * 32;
    const size_t vbase = (size_t)b * CDIM * NTOT;
    unsigned short* PsW = &Ks[(size_t)w * 16 * 136];   // wave-private P region

    // Q B-fragments direct from global: B[k=c][n=i], i = w*16+l15
    f16x8 bQ[4];
    {
        const size_t qrow = ((size_t)b * NTOT + i0 + w * 16 + l15) * CDIM;
        #pragma unroll
        for (int f = 0; f < 4; ++f)
            bQ[f] = *(const f16x8*)&qg[qrow + f * 32 + quad * 8];
    }

    floatx4 accO[8];
    #pragma unroll
    for (int dt = 0; dt < 8; ++dt) accO[dt] = (floatx4){0.f, 0.f, 0.f, 0.f};
    float m_run = -INFINITY, l_part = 0.f;

    for (int j0 = 0; j0 < NTOT; j0 += 128) {
        __syncthreads();   // (A) prev iter's PV reads of Vs/PsW done

        // stage K tile [j 128][c 128] and V tile [d 128][j 128]
        {
            const size_t kb_ = ((size_t)b * NTOT + j0) * CDIM;
            #pragma unroll
            for (int r = 0; r < 16; ++r) {
                int flat = r * 128 + t;
                int row = flat >> 4, c16 = (flat & 15) * 8;
                *(uint4*)&Ks[row * 136 + c16] =
                    *(const uint4*)&kg[kb_ + (size_t)row * CDIM + c16];
                *(uint4*)&Vs[row * 136 + c16] =
                    *(const uint4*)&vg[vbase + (size_t)row * NTOT + j0 + c16];
            }
        }
        __syncthreads();   // (B) tiles ready

        // --- T^T[j][i] = K·Q^T : 8 j-tiles (reads ALL Ks rows) ---
        floatx4 accT[8];
        #pragma unroll
        for (int jt = 0; jt < 8; ++jt) {
            accT[jt] = (floatx4){0.f, 0.f, 0.f, 0.f};
            #pragma unroll
            for (int f = 0; f < 4; ++f) {
                f16x8 aK = *(const f16x8*)&Ks[(jt * 16 + l15) * 136 + f * 32 + quad * 8];
                accT[jt] = mfma16(aK, bQ[f], accT[jt]);
            }
        }

        // --- online softmax (per-lane; lane = one query) ---
        float tm = accT[0][0];
        #pragma unroll
        for (int jt = 0; jt < 8; ++jt)
            #pragma unroll
            for (int r = 0; r < 4; ++r) tm = fmaxf(tm, accT[jt][r]);
        tm = fmaxf(tm, __shfl_xor(tm, 16));
        tm = fmaxf(tm, __shfl_xor(tm, 32));
        const float m_new = fmaxf(m_run, tm);
        const float alpha = __expf(m_run - m_new);   // 0 on first tile
        m_run = m_new;

        float psum = 0.f;
        ushort4 pu[8];   // packed P held in regs until barrier C
        #pragma unroll
        for (int jt = 0; jt < 8; ++jt) {
            float p0 = __expf(accT[jt][0] - m_new);
            float p1 = __expf(accT[jt][1] - m_new);
            float p2 = __expf(accT[jt][2] - m_new);
            float p3 = __expf(accT[jt][3] - m_new);
            psum += (p0 + p1) + (p2 + p3);
            pu[jt].x = f2h(p0); pu[jt].y = f2h(p1);
            pu[jt].z = f2h(p2); pu[jt].w = f2h(p3);
        }
        l_part = l_part * alpha + psum;
        #pragma unroll
        for (int dt = 0; dt < 8; ++dt) {
            accO[dt][0] *= alpha; accO[dt][1] *= alpha;
            accO[dt][2] *= alpha; accO[dt][3] *= alpha;
        }

        __syncthreads();   // (C) all waves' S reads of Ks done -> Ps overlay safe
        #pragma unroll
        for (int jt = 0; jt < 8; ++jt)
            *(ushort4*)&PsW[l15 * 136 + jt * 16 + quad * 4] = pu[jt];

        // --- O^T += V^T·P^T (wave-private P; in-wave lgkmcnt ordering) ---
        f16x8 bP[4];
        #pragma unroll
        for (int kb = 0; kb < 4; ++kb)
            bP[kb] = *(const f16x8*)&PsW[l15 * 136 + kb * 32 + quad * 8];
        #pragma unroll
        for (int dt = 0; dt < 8; ++dt)
            #pragma unroll
            for (int kb = 0; kb < 4; ++kb) {
                f16x8 aV = *(const f16x8*)&Vs[(dt * 16 + l15) * 136 + kb * 32 + quad * 8];
                accO[dt] = mfma16(aV, bP[kb], accO[dt]);
            }
    }

    // final l over quads; store normalized O^T[d][i] as ao[b][i][d] fp16
    float lf = l_part;
    lf += __shfl_xor(lf, 16);
    lf += __shfl_xor(lf, 32);
    const float inv = 1.0f / lf;
    const size_t orow = ((size_t)b * NTOT + i0 + w * 16 + l15) * CDIM;
    #pragma unroll
    for (int dt = 0; dt < 8; ++dt) {
        ushort4 u;
        u.x = f2h(accO[dt][0] * inv); u.y = f2h(accO[dt][1] * inv);
        u.z = f2h(accO[dt][2] * inv); u.w = f2h(accO[dt][3] * inv);
        *(ushort4*)&aog[orow + dt * 16 + quad * 4] = u;
    }
}

// ---------------------------------------------------------------------------
// Output projection + residual, MFMA. ao: [b][n][128] fp16.
// out[b][o][n] = Wo·ao^T + bo + x. grid (64, 4, 2 o-halves), 256 threads.
// ---------------------------------------------------------------------------
__global__ __launch_bounds__(256) void out_proj_kernel(
    const unsigned short* __restrict__ ao,
    const float* __restrict__ Wo, const float* __restrict__ bo,
    const float* __restrict__ x, float* __restrict__ out)
{
    __shared__ __align__(16) unsigned short As[64][136];  // [n][c]
    __shared__ __align__(16) unsigned short Ws[64][136];  // [o-half][c]

    const int t = threadIdx.x, b = blockIdx.y, n0 = blockIdx.x * 64;
    const int zo = blockIdx.z * 64;
    const int w = t >> 6, quad = (t >> 4) & 3, l15 = t & 15;

    #pragma unroll
    for (int r = 0; r < 4; ++r) {   // stage ao tile (direct fp16 copy)
        int flat = r * 256 + t;
        int row = flat >> 4, c16 = (flat & 15) * 8;
        *(uint4*)&As[row][c16] =
            *(const uint4*)&ao[((size_t)b * NTOT + n0 + row) * CDIM + c16];
    }
    {
        int o = t >> 2, ch = (t & 3) * 32;
        #pragma unroll
        for (int i = 0; i < 8; ++i) {
            float4 f4 = *(const float4*)&Wo[(size_t)(zo + o) * CDIM + ch + i * 4];
            ushort4 u = { f2h(f4.x), f2h(f4.y), f2h(f4.z), f2h(f4.w) };
            *(ushort4*)&Ws[o][ch + i * 4] = u;
        }
    }
    __syncthreads();

    f16x8 bA[4];
    #pragma unroll
    for (int f = 0; f < 4; ++f)
        bA[f] = *(const f16x8*)&As[w * 16 + l15][f * 32 + quad * 8];

    #pragma unroll
    for (int ot = 0; ot < 4; ++ot) {
        floatx4 acc = (floatx4){0.f, 0.f, 0.f, 0.f};
        #pragma unroll
        for (int f = 0; f < 4; ++f) {
            f16x8 aW = *(const f16x8*)&Ws[ot * 16 + l15][f * 32 + quad * 8];
            acc = mfma16(aW, bA[f], acc);
        }
        const int ob = zo + ot * 16 + quad * 4;
        #pragma unroll
        for (int r = 0; r < 4; ++r) {
            size_t idx = ((size_t)b * CDIM + ob + r) * NTOT + n0 + w * 16 + l15;
            out[idx] = acc[r] + bo[ob + r] + x[idx];
        }
    }
}

// ---------------------------------------------------------------------------
extern "C" void kernel_launch(void* const* d_in, const int* in_sizes, int n_in,
                              void* d_out, int out_size, void* d_ws, size_t ws_size,
                              hipStream_t stream)
{
    const float* x  = (const float*)d_in[0];
    const float* Wq = (const float*)d_in[1];
    const float* bq = (const float*)d_in[2];
    const float* Wk = (const float*)d_in[3];
    const float* bk = (const float*)d_in[4];
    const float* Wv = (const float*)d_in[5];
    const float* bv = (const float*)d_in[6];
    const float* Wo = (const float*)d_in[7];
    const float* bo = (const float*)d_in[8];
    float* out = (float*)d_out;

    const size_t PER = (size_t)4 * CDIM * NTOT;   // 2,097,152 elements
    unsigned short* q_ws  = (unsigned short*)d_ws;
    unsigned short* k_ws  = q_ws + PER;
    unsigned short* v_ws  = k_ws + PER;
    unsigned short* ao_ws = v_ws + PER;           // fp16 [b][n][c]

    qkv_proj_kernel<<<dim3(64, 4, 2), dim3(256), 0, stream>>>(
        x, Wq, bq, Wk, bk, Wv, bv, q_ws, k_ws, v_ws);
    attn_kernel<<<dim3(128, 4), dim3(128), 0, stream>>>(q_ws, k_ws, v_ws, ao_ws);
    out_proj_kernel<<<dim3(64, 4, 2), dim3(256), 0, stream>>>(ao_ws, Wo, bo, x, out);
}

// Round 9
// 168.603 us; speedup vs baseline: 2.6279x; 2.6279x over previous
//
#include <hip/hip_runtime.h>
#include <math.h>
#include <stdint.h>

#define CDIM 128
#define NTOT 4096

typedef _Float16 f16x8 __attribute__((ext_vector_type(8)));  // 8 fp16 (4 VGPRs)
typedef float floatx4 __attribute__((ext_vector_type(4)));   // MFMA accumulator

static __device__ __forceinline__ floatx4 mfma16(f16x8 a, f16x8 b, floatx4 c) {
    return __builtin_amdgcn_mfma_f32_16x16x32_f16(a, b, c, 0, 0, 0);
}
static __device__ __forceinline__ unsigned short f2h(float f) {
    _Float16 h = (_Float16)f;
    return __builtin_bit_cast(unsigned short, h);
}
static __device__ __forceinline__ float h2f(unsigned short u) {
    return (float)__builtin_bit_cast(_Float16, u);
}

// ---------------------------------------------------------------------------
// Fused q/k/v projection, MFMA. x: [4][128][4096] fp32.
// Outputs fp16: qo, ko: [b][n][c]; vo: [b][c][n].
// grid (64 n-tiles, 4 batches, 2 o-halves), 256 threads / 4 waves.
// ---------------------------------------------------------------------------
__global__ __launch_bounds__(256) void qkv_proj_kernel(
    const float* __restrict__ x,
    const float* __restrict__ Wq, const float* __restrict__ bq,
    const float* __restrict__ Wk, const float* __restrict__ bk,
    const float* __restrict__ Wv, const float* __restrict__ bv,
    unsigned short* __restrict__ qo, unsigned short* __restrict__ ko,
    unsigned short* __restrict__ vo)
{
    __shared__ __align__(16) unsigned short Xs[64][136];   // [n][c] fp16
    __shared__ __align__(16) unsigned short Ws[64][136];   // [o-half][c] fp16

    const int t = threadIdx.x, b = blockIdx.y, n0 = blockIdx.x * 64;
    const int zo = blockIdx.z * 64;
    const int w = t >> 6, quad = (t >> 4) & 3, l15 = t & 15;

    // stage x tile with transpose-on-store: thread covers 4n x 8c
    {
        const int n = (t & 15) * 4;
        const int c = (t >> 4) * 8;
        float4 xr[8];
        #pragma unroll
        for (int j = 0; j < 8; ++j)
            xr[j] = *(const float4*)&x[((size_t)b * CDIM + c + j) * NTOT + n0 + n];
        #pragma unroll
        for (int k = 0; k < 4; ++k) {
            ushort4 ulo, uhi;
            ulo.x = f2h(((const float*)&xr[0])[k]);
            ulo.y = f2h(((const float*)&xr[1])[k]);
            ulo.z = f2h(((const float*)&xr[2])[k]);
            ulo.w = f2h(((const float*)&xr[3])[k]);
            uhi.x = f2h(((const float*)&xr[4])[k]);
            uhi.y = f2h(((const float*)&xr[5])[k]);
            uhi.z = f2h(((const float*)&xr[6])[k]);
            uhi.w = f2h(((const float*)&xr[7])[k]);
            *(ushort4*)&Xs[n + k][c]     = ulo;
            *(ushort4*)&Xs[n + k][c + 4] = uhi;
        }
    }

    f16x8 xf[4];
    for (int s = 0; s < 3; ++s) {
        const float* W    = (s == 0) ? Wq : (s == 1) ? Wk : Wv;
        const float* bias = (s == 0) ? bq : (s == 1) ? bk : bv;
        if (s) __syncthreads();   // previous Ws readers done
        {
            int o = t >> 2, ch = (t & 3) * 32;
            #pragma unroll
            for (int i = 0; i < 8; ++i) {
                float4 f4 = *(const float4*)&W[(size_t)(zo + o) * CDIM + ch + i * 4];
                ushort4 u = { f2h(f4.x), f2h(f4.y), f2h(f4.z), f2h(f4.w) };
                *(ushort4*)&Ws[o][ch + i * 4] = u;
            }
        }
        __syncthreads();          // Ws (and on s==0, Xs) ready
        if (s == 0) {
            #pragma unroll
            for (int f = 0; f < 4; ++f)
                xf[f] = *(const f16x8*)&Xs[w * 16 + l15][f * 32 + quad * 8];
        }

        if (s < 2) {   // q, k: C[o][n], A = W, B = X
            unsigned short* dst = (s == 0) ? qo : ko;
            #pragma unroll
            for (int ot = 0; ot < 4; ++ot) {
                floatx4 acc = (floatx4){0.f, 0.f, 0.f, 0.f};
                #pragma unroll
                for (int f = 0; f < 4; ++f) {
                    f16x8 aW = *(const f16x8*)&Ws[ot * 16 + l15][f * 32 + quad * 8];
                    acc = mfma16(aW, xf[f], acc);
                }
                const int ob = zo + ot * 16 + quad * 4;
                ushort4 u;
                u.x = f2h(acc[0] + bias[ob + 0]);
                u.y = f2h(acc[1] + bias[ob + 1]);
                u.z = f2h(acc[2] + bias[ob + 2]);
                u.w = f2h(acc[3] + bias[ob + 3]);
                *(ushort4*)&dst[((size_t)b * NTOT + n0 + w * 16 + l15) * CDIM + ob] = u;
            }
        } else {       // v: C'[n][o], A = X, B = W
            #pragma unroll
            for (int ot = 0; ot < 4; ++ot) {
                floatx4 acc = (floatx4){0.f, 0.f, 0.f, 0.f};
                #pragma unroll
                for (int f = 0; f < 4; ++f) {
                    f16x8 bW = *(const f16x8*)&Ws[ot * 16 + l15][f * 32 + quad * 8];
                    acc = mfma16(xf[f], bW, acc);
                }
                const int o = zo + ot * 16 + l15;
                const float bv_ = bias[o];
                ushort4 u;
                u.x = f2h(acc[0] + bv_); u.y = f2h(acc[1] + bv_);
                u.z = f2h(acc[2] + bv_); u.w = f2h(acc[3] + bv_);
                *(ushort4*)&vo[((size_t)b * CDIM + o) * NTOT + n0 + w * 16 + quad * 4] = u;
            }
        }
    }
}

// ---------------------------------------------------------------------------
// Flash attention, split-K(4). q,k: [b][n][128] fp16; v: [b][128][n] fp16.
// grid (32 q-tiles, 4 batches, 4 key-quarters), 256 threads / 4 waves.
// BQ=128: wave w owns 32 queries (2 n-tiles) end-to-end; KT=128, 8 iters
// over this block's 1024-key quarter. Each aK/aV LDS read feeds TWO MFMAs
// (2 q-tiles) -> half the LDS-read traffic per FLOP of R6/R7/R8.
// NO register prefetch (spill hazard). Ps overlaid on Ks after barrier C.
// LDS 69.6 KB -> 2 co-resident blocks/CU. Partials self-normalized + stats.
// ---------------------------------------------------------------------------
__global__ __launch_bounds__(256, 2) void attn_kernel(
    const unsigned short* __restrict__ qg,
    const unsigned short* __restrict__ kg,
    const unsigned short* __restrict__ vg,
    unsigned short* __restrict__ Op,
    float* __restrict__ Ms, float* __restrict__ Ls)
{
    __shared__ __align__(16) unsigned short Ks[128 * 136];   // [j][c] 34.8 KB (becomes Ps after C)
    __shared__ __align__(16) unsigned short Vs[128 * 136];   // [d][j] 34.8 KB

    const int t = threadIdx.x;
    const int w = t >> 6, quad = (t >> 4) & 3, l15 = t & 15;
    const int b = blockIdx.y;
    const int z = blockIdx.z;
    const int i0 = blockIdx.x * 128;
    const int jbase = z * 1024;
    const size_t vbase = (size_t)b * CDIM * NTOT;
    unsigned short* PsW = &Ks[(size_t)w * 32 * 136];   // wave-private P: 32 q-rows

    // Q B-fragments direct from global: wave owns queries i0 + w*32 + nt*16 + l15
    f16x8 bQ[2][4];
    #pragma unroll
    for (int nt = 0; nt < 2; ++nt) {
        const size_t qrow = ((size_t)b * NTOT + i0 + w * 32 + nt * 16 + l15) * CDIM;
        #pragma unroll
        for (int f = 0; f < 4; ++f)
            bQ[nt][f] = *(const f16x8*)&qg[qrow + f * 32 + quad * 8];
    }

    floatx4 accO[2][8];   // [nt][dt]
    #pragma unroll
    for (int nt = 0; nt < 2; ++nt)
        #pragma unroll
        for (int dt = 0; dt < 8; ++dt) accO[nt][dt] = (floatx4){0.f, 0.f, 0.f, 0.f};
    float m_run[2] = {-INFINITY, -INFINITY};
    float l_part[2] = {0.f, 0.f};

    for (int iter = 0; iter < 8; ++iter) {
        const int j0 = jbase + iter * 128;
        __syncthreads();   // (A) prev iter's PV reads of Vs/PsW done

        // stage K tile [j 128][c 128] and V tile [d 128][j 128] cooperatively
        {
            const size_t kb_ = ((size_t)b * NTOT + j0) * CDIM;
            #pragma unroll
            for (int r = 0; r < 8; ++r) {
                int flat = r * 256 + t;
                int row = flat >> 4, c16 = (flat & 15) * 8;
                *(uint4*)&Ks[row * 136 + c16] =
                    *(const uint4*)&kg[kb_ + (size_t)row * CDIM + c16];
                *(uint4*)&Vs[row * 136 + c16] =
                    *(const uint4*)&vg[vbase + (size_t)row * NTOT + j0 + c16];
            }
        }
        __syncthreads();   // (B) tiles ready

        // --- T^T[j][i] = K·Q^T : 8 j-tiles x 2 q-tiles (1 aK read -> 2 MFMA) ---
        floatx4 accT[2][8];
        #pragma unroll
        for (int nt = 0; nt < 2; ++nt)
            #pragma unroll
            for (int jt = 0; jt < 8; ++jt) accT[nt][jt] = (floatx4){0.f, 0.f, 0.f, 0.f};
        #pragma unroll
        for (int jt = 0; jt < 8; ++jt)
            #pragma unroll
            for (int f = 0; f < 4; ++f) {
                f16x8 aK = *(const f16x8*)&Ks[(jt * 16 + l15) * 136 + f * 32 + quad * 8];
                accT[0][jt] = mfma16(aK, bQ[0][f], accT[0][jt]);
                accT[1][jt] = mfma16(aK, bQ[1][f], accT[1][jt]);
            }

        // --- online softmax per q-tile (per-lane; lane = one query) ---
        float m_new[2], alpha[2], psum[2];
        ushort4 pu[2][8];
        #pragma unroll
        for (int nt = 0; nt < 2; ++nt) {
            float tm = accT[nt][0][0];
            #pragma unroll
            for (int jt = 0; jt < 8; ++jt)
                #pragma unroll
                for (int r = 0; r < 4; ++r) tm = fmaxf(tm, accT[nt][jt][r]);
            tm = fmaxf(tm, __shfl_xor(tm, 16));
            tm = fmaxf(tm, __shfl_xor(tm, 32));
            m_new[nt] = fmaxf(m_run[nt], tm);
            alpha[nt] = __expf(m_run[nt] - m_new[nt]);   // 0 on first tile
            m_run[nt] = m_new[nt];
            float ps = 0.f;
            #pragma unroll
            for (int jt = 0; jt < 8; ++jt) {
                float p0 = __expf(accT[nt][jt][0] - m_new[nt]);
                float p1 = __expf(accT[nt][jt][1] - m_new[nt]);
                float p2 = __expf(accT[nt][jt][2] - m_new[nt]);
                float p3 = __expf(accT[nt][jt][3] - m_new[nt]);
                ps += (p0 + p1) + (p2 + p3);
                pu[nt][jt].x = f2h(p0); pu[nt][jt].y = f2h(p1);
                pu[nt][jt].z = f2h(p2); pu[nt][jt].w = f2h(p3);
            }
            psum[nt] = ps;
            l_part[nt] = l_part[nt] * alpha[nt] + ps;
            #pragma unroll
            for (int dt = 0; dt < 8; ++dt) {
                accO[nt][dt][0] *= alpha[nt]; accO[nt][dt][1] *= alpha[nt];
                accO[nt][dt][2] *= alpha[nt]; accO[nt][dt][3] *= alpha[nt];
            }
        }

        __syncthreads();   // (C) all waves' S reads of Ks done -> Ps overlay safe
        #pragma unroll
        for (int nt = 0; nt < 2; ++nt)
            #pragma unroll
            for (int jt = 0; jt < 8; ++jt)
                *(ushort4*)&PsW[(nt * 16 + l15) * 136 + jt * 16 + quad * 4] = pu[nt][jt];

        // --- O^T += V·P^T (wave-private P; 1 aV read -> 2 MFMA) ---
        f16x8 bP[2][4];
        #pragma unroll
        for (int nt = 0; nt < 2; ++nt)
            #pragma unroll
            for (int kb = 0; kb < 4; ++kb)
                bP[nt][kb] = *(const f16x8*)&PsW[(nt * 16 + l15) * 136 + kb * 32 + quad * 8];
        #pragma unroll
        for (int dt = 0; dt < 8; ++dt)
            #pragma unroll
            for (int kb = 0; kb < 4; ++kb) {
                f16x8 aV = *(const f16x8*)&Vs[(dt * 16 + l15) * 136 + kb * 32 + quad * 8];
                accO[0][dt] = mfma16(aV, bP[0][kb], accO[0][dt]);
                accO[1][dt] = mfma16(aV, bP[1][kb], accO[1][dt]);
            }
    }

    // final l over quads; store normalized partials + stats
    #pragma unroll
    for (int nt = 0; nt < 2; ++nt) {
        float lf = l_part[nt];
        lf += __shfl_xor(lf, 16);
        lf += __shfl_xor(lf, 32);
        const float inv = 1.0f / lf;
        const size_t orow =
            (((size_t)z * 4 + b) * NTOT + i0 + w * 32 + nt * 16 + l15) * CDIM;
        #pragma unroll
        for (int dt = 0; dt < 8; ++dt) {
            ushort4 u;
            u.x = f2h(accO[nt][dt][0] * inv); u.y = f2h(accO[nt][dt][1] * inv);
            u.z = f2h(accO[nt][dt][2] * inv); u.w = f2h(accO[nt][dt][3] * inv);
            *(ushort4*)&Op[orow + dt * 16 + quad * 4] = u;
        }
        if (quad == 0) {
            const int idx = (z * 4 + b) * NTOT + i0 + w * 32 + nt * 16 + l15;
            Ms[idx] = m_run[nt];
            Ls[idx] = lf;
        }
    }
}

// ---------------------------------------------------------------------------
// Merge the four key-quarter partials: ao = sum_z wz*Oz, wz = lz*e^{mz-M}/sum.
// grid 1024 x 256 threads, 8 fp16 (16 B) per thread. ao may alias Op[0]
// (each thread reads its own 16 B before writing them).
// ---------------------------------------------------------------------------
__global__ __launch_bounds__(256) void combine_kernel(
    const unsigned short* __restrict__ Op,
    const float* __restrict__ Ms, const float* __restrict__ Ls,
    unsigned short* __restrict__ ao)
{
    const int tid = blockIdx.x * 256 + threadIdx.x;     // 0..262143
    const size_t e8 = (size_t)tid * 8;
    const int bn = tid >> 4;                            // b*4096+n (16 thr/row)
    float m0 = Ms[bn], m1 = Ms[bn + 16384], m2 = Ms[bn + 32768], m3 = Ms[bn + 49152];
    float M = fmaxf(fmaxf(m0, m1), fmaxf(m2, m3));
    float w0 = Ls[bn]         * __expf(m0 - M);
    float w1 = Ls[bn + 16384] * __expf(m1 - M);
    float w2 = Ls[bn + 32768] * __expf(m2 - M);
    float w3 = Ls[bn + 49152] * __expf(m3 - M);
    const float inv = 1.0f / (w0 + w1 + w2 + w3);
    w0 *= inv; w1 *= inv; w2 *= inv; w3 *= inv;

    uint4 a0 = *(const uint4*)&Op[e8];
    uint4 a1 = *(const uint4*)&Op[(size_t)2097152 + e8];
    uint4 a2 = *(const uint4*)&Op[(size_t)4194304 + e8];
    uint4 a3 = *(const uint4*)&Op[(size_t)6291456 + e8];
    const unsigned short* p0 = (const unsigned short*)&a0;
    const unsigned short* p1 = (const unsigned short*)&a1;
    const unsigned short* p2 = (const unsigned short*)&a2;
    const unsigned short* p3 = (const unsigned short*)&a3;
    unsigned short ov[8];
    #pragma unroll
    for (int j = 0; j < 8; ++j)
        ov[j] = f2h(w0 * h2f(p0[j]) + w1 * h2f(p1[j]) +
                    w2 * h2f(p2[j]) + w3 * h2f(p3[j]));
    *(uint4*)&ao[e8] = *(const uint4*)ov;
}

// ---------------------------------------------------------------------------
// Output projection + residual, MFMA. ao: [b][n][128] fp16.
// out[b][o][n] = Wo·ao^T + bo + x. grid (64, 4, 2 o-halves), 256 threads.
// ---------------------------------------------------------------------------
__global__ __launch_bounds__(256) void out_proj_kernel(
    const unsigned short* __restrict__ ao,
    const float* __restrict__ Wo, const float* __restrict__ bo,
    const float* __restrict__ x, float* __restrict__ out)
{
    __shared__ __align__(16) unsigned short As[64][136];  // [n][c]
    __shared__ __align__(16) unsigned short Ws[64][136];  // [o-half][c]

    const int t = threadIdx.x, b = blockIdx.y, n0 = blockIdx.x * 64;
    const int zo = blockIdx.z * 64;
    const int w = t >> 6, quad = (t >> 4) & 3, l15 = t & 15;

    #pragma unroll
    for (int r = 0; r < 4; ++r) {   // stage ao tile (direct fp16 copy)
        int flat = r * 256 + t;
        int row = flat >> 4, c16 = (flat & 15) * 8;
        *(uint4*)&As[row][c16] =
            *(const uint4*)&ao[((size_t)b * NTOT + n0 + row) * CDIM + c16];
    }
    {
        int o = t >> 2, ch = (t & 3) * 32;
        #pragma unroll
        for (int i = 0; i < 8; ++i) {
            float4 f4 = *(const float4*)&Wo[(size_t)(zo + o) * CDIM + ch + i * 4];
            ushort4 u = { f2h(f4.x), f2h(f4.y), f2h(f4.z), f2h(f4.w) };
            *(ushort4*)&Ws[o][ch + i * 4] = u;
        }
    }
    __syncthreads();

    f16x8 bA[4];
    #pragma unroll
    for (int f = 0; f < 4; ++f)
        bA[f] = *(const f16x8*)&As[w * 16 + l15][f * 32 + quad * 8];

    #pragma unroll
    for (int ot = 0; ot < 4; ++ot) {
        floatx4 acc = (floatx4){0.f, 0.f, 0.f, 0.f};
        #pragma unroll
        for (int f = 0; f < 4; ++f) {
            f16x8 aW = *(const f16x8*)&Ws[ot * 16 + l15][f * 32 + quad * 8];
            acc = mfma16(aW, bA[f], acc);
        }
        const int ob = zo + ot * 16 + quad * 4;
        #pragma unroll
        for (int r = 0; r < 4; ++r) {
            size_t idx = ((size_t)b * CDIM + ob + r) * NTOT + n0 + w * 16 + l15;
            out[idx] = acc[r] + bo[ob + r] + x[idx];
        }
    }
}

// ---------------------------------------------------------------------------
extern "C" void kernel_launch(void* const* d_in, const int* in_sizes, int n_in,
                              void* d_out, int out_size, void* d_ws, size_t ws_size,
                              hipStream_t stream)
{
    const float* x  = (const float*)d_in[0];
    const float* Wq = (const float*)d_in[1];
    const float* bq = (const float*)d_in[2];
    const float* Wk = (const float*)d_in[3];
    const float* bk = (const float*)d_in[4];
    const float* Wv = (const float*)d_in[5];
    const float* bv = (const float*)d_in[6];
    const float* Wo = (const float*)d_in[7];
    const float* bo = (const float*)d_in[8];
    float* out = (float*)d_out;

    const size_t PER = (size_t)4 * CDIM * NTOT;   // 2,097,152 elements
    unsigned short* q_ws  = (unsigned short*)d_ws;
    unsigned short* k_ws  = q_ws + PER;
    unsigned short* v_ws  = k_ws + PER;
    unsigned short* op_ws = v_ws + PER;           // fp16 [4][b][n][c] partials
    unsigned short* ao_ws = op_ws;                // combine output aliases Op[0]
    float*          ms_ws = (float*)(op_ws + 4 * PER);   // [4][b*n]
    float*          ls_ws = ms_ws + 4 * 16384;

    qkv_proj_kernel<<<dim3(64, 4, 2), dim3(256), 0, stream>>>(
        x, Wq, bq, Wk, bk, Wv, bv, q_ws, k_ws, v_ws);
    attn_kernel<<<dim3(32, 4, 4), dim3(256), 0, stream>>>(
        q_ws, k_ws, v_ws, op_ws, ms_ws, ls_ws);
    combine_kernel<<<dim3(1024), dim3(256), 0, stream>>>(op_ws, ms_ws, ls_ws, ao_ws);
    out_proj_kernel<<<dim3(64, 4, 2), dim3(256), 0, stream>>>(ao_ws, Wo, bo, x, out);
}

// Round 10
// 166.922 us; speedup vs baseline: 2.6544x; 1.0101x over previous
//
#include <hip/hip_runtime.h>
#include <math.h>
#include <stdint.h>

#define CDIM 128
#define NTOT 4096

typedef _Float16 f16x8 __attribute__((ext_vector_type(8)));  // 8 fp16 (4 VGPRs)
typedef float floatx4 __attribute__((ext_vector_type(4)));   // MFMA accumulator

static __device__ __forceinline__ floatx4 mfma16(f16x8 a, f16x8 b, floatx4 c) {
    return __builtin_amdgcn_mfma_f32_16x16x32_f16(a, b, c, 0, 0, 0);
}
static __device__ __forceinline__ unsigned short f2h(float f) {
    _Float16 h = (_Float16)f;
    return __builtin_bit_cast(unsigned short, h);
}
static __device__ __forceinline__ float h2f(unsigned short u) {
    return (float)__builtin_bit_cast(_Float16, u);
}

// XOR-swizzled LDS addressing: rows of 128 ush (no pad, stride = 64 words =
// 2 full bank sweeps), 16-B chunk cc (0..15) stored at cc ^ (row & 15).
// - staging writes (lane=cc, fixed row): perm(cc) -> banks 4k..4k+3, full spread
// - fragment reads (lane=row+l15, fixed cc): cc^l15 = perm -> full spread
#define SWZ(row, cc) ((((row) << 7)) + ((((cc) ^ ((row) & 15))) << 3))

// ---------------------------------------------------------------------------
// Fused q/k/v projection, MFMA. x: [4][128][4096] fp32.
// Outputs fp16: qo, ko: [b][n][c]; vo: [b][c][n].
// grid (64 n-tiles, 4 batches, 2 o-halves), 256 threads / 4 waves.
// ---------------------------------------------------------------------------
__global__ __launch_bounds__(256) void qkv_proj_kernel(
    const float* __restrict__ x,
    const float* __restrict__ Wq, const float* __restrict__ bq,
    const float* __restrict__ Wk, const float* __restrict__ bk,
    const float* __restrict__ Wv, const float* __restrict__ bv,
    unsigned short* __restrict__ qo, unsigned short* __restrict__ ko,
    unsigned short* __restrict__ vo)
{
    __shared__ __align__(16) unsigned short Xs[64][136];   // [n][c] fp16
    __shared__ __align__(16) unsigned short Ws[64][136];   // [o-half][c] fp16

    const int t = threadIdx.x, b = blockIdx.y, n0 = blockIdx.x * 64;
    const int zo = blockIdx.z * 64;
    const int w = t >> 6, quad = (t >> 4) & 3, l15 = t & 15;

    // stage x tile with transpose-on-store: thread covers 4n x 8c
    {
        const int n = (t & 15) * 4;
        const int c = (t >> 4) * 8;
        float4 xr[8];
        #pragma unroll
        for (int j = 0; j < 8; ++j)
            xr[j] = *(const float4*)&x[((size_t)b * CDIM + c + j) * NTOT + n0 + n];
        #pragma unroll
        for (int k = 0; k < 4; ++k) {
            ushort4 ulo, uhi;
            ulo.x = f2h(((const float*)&xr[0])[k]);
            ulo.y = f2h(((const float*)&xr[1])[k]);
            ulo.z = f2h(((const float*)&xr[2])[k]);
            ulo.w = f2h(((const float*)&xr[3])[k]);
            uhi.x = f2h(((const float*)&xr[4])[k]);
            uhi.y = f2h(((const float*)&xr[5])[k]);
            uhi.z = f2h(((const float*)&xr[6])[k]);
            uhi.w = f2h(((const float*)&xr[7])[k]);
            *(ushort4*)&Xs[n + k][c]     = ulo;
            *(ushort4*)&Xs[n + k][c + 4] = uhi;
        }
    }

    f16x8 xf[4];
    for (int s = 0; s < 3; ++s) {
        const float* W    = (s == 0) ? Wq : (s == 1) ? Wk : Wv;
        const float* bias = (s == 0) ? bq : (s == 1) ? bk : bv;
        if (s) __syncthreads();   // previous Ws readers done
        {
            int o = t >> 2, ch = (t & 3) * 32;
            #pragma unroll
            for (int i = 0; i < 8; ++i) {
                float4 f4 = *(const float4*)&W[(size_t)(zo + o) * CDIM + ch + i * 4];
                ushort4 u = { f2h(f4.x), f2h(f4.y), f2h(f4.z), f2h(f4.w) };
                *(ushort4*)&Ws[o][ch + i * 4] = u;
            }
        }
        __syncthreads();          // Ws (and on s==0, Xs) ready
        if (s == 0) {
            #pragma unroll
            for (int f = 0; f < 4; ++f)
                xf[f] = *(const f16x8*)&Xs[w * 16 + l15][f * 32 + quad * 8];
        }

        if (s < 2) {   // q, k: C[o][n], A = W, B = X
            unsigned short* dst = (s == 0) ? qo : ko;
            #pragma unroll
            for (int ot = 0; ot < 4; ++ot) {
                floatx4 acc = (floatx4){0.f, 0.f, 0.f, 0.f};
                #pragma unroll
                for (int f = 0; f < 4; ++f) {
                    f16x8 aW = *(const f16x8*)&Ws[ot * 16 + l15][f * 32 + quad * 8];
                    acc = mfma16(aW, xf[f], acc);
                }
                const int ob = zo + ot * 16 + quad * 4;
                ushort4 u;
                u.x = f2h(acc[0] + bias[ob + 0]);
                u.y = f2h(acc[1] + bias[ob + 1]);
                u.z = f2h(acc[2] + bias[ob + 2]);
                u.w = f2h(acc[3] + bias[ob + 3]);
                *(ushort4*)&dst[((size_t)b * NTOT + n0 + w * 16 + l15) * CDIM + ob] = u;
            }
        } else {       // v: C'[n][o], A = X, B = W
            #pragma unroll
            for (int ot = 0; ot < 4; ++ot) {
                floatx4 acc = (floatx4){0.f, 0.f, 0.f, 0.f};
                #pragma unroll
                for (int f = 0; f < 4; ++f) {
                    f16x8 bW = *(const f16x8*)&Ws[ot * 16 + l15][f * 32 + quad * 8];
                    acc = mfma16(xf[f], bW, acc);
                }
                const int o = zo + ot * 16 + l15;
                const float bv_ = bias[o];
                ushort4 u;
                u.x = f2h(acc[0] + bv_); u.y = f2h(acc[1] + bv_);
                u.z = f2h(acc[2] + bv_); u.w = f2h(acc[3] + bv_);
                *(ushort4*)&vo[((size_t)b * CDIM + o) * NTOT + n0 + w * 16 + quad * 4] = u;
            }
        }
    }
}

// ---------------------------------------------------------------------------
// Flash attention, split-K(4), XOR-swizzled LDS (R9 dataflow otherwise).
// q,k: [b][n][128] fp16; v: [b][128][n] fp16.
// grid (32 q-tiles, 4 batches, 4 key-quarters), 256 threads / 4 waves.
// BQ=128: wave w owns 32 queries (2 n-tiles); KT=128, 8 iters per quarter.
// Each aK/aV LDS read feeds TWO MFMAs. Ps overlaid on Ks after barrier C.
// LDS 64 KB -> 2 co-resident blocks/CU. Partials self-normalized + stats.
// ---------------------------------------------------------------------------
__global__ __launch_bounds__(256, 2) void attn_kernel(
    const unsigned short* __restrict__ qg,
    const unsigned short* __restrict__ kg,
    const unsigned short* __restrict__ vg,
    unsigned short* __restrict__ Op,
    float* __restrict__ Ms, float* __restrict__ Ls)
{
    __shared__ __align__(16) unsigned short Ks[128 * 128];   // [j][c] 32 KB (becomes Ps after C)
    __shared__ __align__(16) unsigned short Vs[128 * 128];   // [d][j] 32 KB

    const int t = threadIdx.x;
    const int w = t >> 6, quad = (t >> 4) & 3, l15 = t & 15;
    const int b = blockIdx.y;
    const int z = blockIdx.z;
    const int i0 = blockIdx.x * 128;
    const int jbase = z * 1024;
    const size_t vbase = (size_t)b * CDIM * NTOT;

    // Q B-fragments direct from global: wave owns queries i0 + w*32 + nt*16 + l15
    f16x8 bQ[2][4];
    #pragma unroll
    for (int nt = 0; nt < 2; ++nt) {
        const size_t qrow = ((size_t)b * NTOT + i0 + w * 32 + nt * 16 + l15) * CDIM;
        #pragma unroll
        for (int f = 0; f < 4; ++f)
            bQ[nt][f] = *(const f16x8*)&qg[qrow + f * 32 + quad * 8];
    }

    floatx4 accO[2][8];   // [nt][dt]
    #pragma unroll
    for (int nt = 0; nt < 2; ++nt)
        #pragma unroll
        for (int dt = 0; dt < 8; ++dt) accO[nt][dt] = (floatx4){0.f, 0.f, 0.f, 0.f};
    float m_run[2] = {-INFINITY, -INFINITY};
    float l_part[2] = {0.f, 0.f};

    for (int iter = 0; iter < 8; ++iter) {
        const int j0 = jbase + iter * 128;
        __syncthreads();   // (A) prev iter's PV reads of Vs/Ps done

        // stage K tile [j 128][c 128] and V tile [d 128][j 128], swizzled
        {
            const size_t kb_ = ((size_t)b * NTOT + j0) * CDIM;
            #pragma unroll
            for (int r = 0; r < 8; ++r) {
                int flat = r * 256 + t;
                int row = flat >> 4, cc = flat & 15;
                *(uint4*)&Ks[SWZ(row, cc)] =
                    *(const uint4*)&kg[kb_ + (size_t)row * CDIM + cc * 8];
                *(uint4*)&Vs[SWZ(row, cc)] =
                    *(const uint4*)&vg[vbase + (size_t)row * NTOT + j0 + cc * 8];
            }
        }
        __syncthreads();   // (B) tiles ready

        // --- T^T[j][i] = K·Q^T : 8 j-tiles x 2 q-tiles (1 aK read -> 2 MFMA) ---
        floatx4 accT[2][8];
        #pragma unroll
        for (int nt = 0; nt < 2; ++nt)
            #pragma unroll
            for (int jt = 0; jt < 8; ++jt) accT[nt][jt] = (floatx4){0.f, 0.f, 0.f, 0.f};
        #pragma unroll
        for (int jt = 0; jt < 8; ++jt)
            #pragma unroll
            for (int f = 0; f < 4; ++f) {
                f16x8 aK = *(const f16x8*)&Ks[SWZ(jt * 16 + l15, f * 4 + quad)];
                accT[0][jt] = mfma16(aK, bQ[0][f], accT[0][jt]);
                accT[1][jt] = mfma16(aK, bQ[1][f], accT[1][jt]);
            }

        // --- online softmax per q-tile (per-lane; lane = one query) ---
        float m_new[2], alpha[2];
        ushort4 pu[2][8];
        #pragma unroll
        for (int nt = 0; nt < 2; ++nt) {
            float tm = accT[nt][0][0];
            #pragma unroll
            for (int jt = 0; jt < 8; ++jt)
                #pragma unroll
                for (int r = 0; r < 4; ++r) tm = fmaxf(tm, accT[nt][jt][r]);
            tm = fmaxf(tm, __shfl_xor(tm, 16));
            tm = fmaxf(tm, __shfl_xor(tm, 32));
            m_new[nt] = fmaxf(m_run[nt], tm);
            alpha[nt] = __expf(m_run[nt] - m_new[nt]);   // 0 on first tile
            m_run[nt] = m_new[nt];
            float ps = 0.f;
            #pragma unroll
            for (int jt = 0; jt < 8; ++jt) {
                float p0 = __expf(accT[nt][jt][0] - m_new[nt]);
                float p1 = __expf(accT[nt][jt][1] - m_new[nt]);
                float p2 = __expf(accT[nt][jt][2] - m_new[nt]);
                float p3 = __expf(accT[nt][jt][3] - m_new[nt]);
                ps += (p0 + p1) + (p2 + p3);
                pu[nt][jt].x = f2h(p0); pu[nt][jt].y = f2h(p1);
                pu[nt][jt].z = f2h(p2); pu[nt][jt].w = f2h(p3);
            }
            l_part[nt] = l_part[nt] * alpha[nt] + ps;
            #pragma unroll
            for (int dt = 0; dt < 8; ++dt) {
                accO[nt][dt][0] *= alpha[nt]; accO[nt][dt][1] *= alpha[nt];
                accO[nt][dt][2] *= alpha[nt]; accO[nt][dt][3] *= alpha[nt];
            }
        }

        __syncthreads();   // (C) all waves' S reads of Ks done -> Ps overlay safe

        // Ps overlay in Ks: wave-private rows prow = w*32 + nt*16 + l15,
        // logical [i][j] row-major; P(j = jt*16 + quad*4 + r) -> chunk
        // cc = 2*jt + (quad>>1), sub-offset (quad&1)*4 ush (b64 write).
        #pragma unroll
        for (int nt = 0; nt < 2; ++nt) {
            const int prow = w * 32 + nt * 16 + l15;
            #pragma unroll
            for (int jt = 0; jt < 8; ++jt)
                *(ushort4*)&Ks[SWZ(prow, 2 * jt + (quad >> 1)) + (quad & 1) * 4] =
                    pu[nt][jt];
        }

        // --- O^T += V·P^T (wave-private P; 1 aV read -> 2 MFMA) ---
        f16x8 bP[2][4];
        #pragma unroll
        for (int nt = 0; nt < 2; ++nt) {
            const int prow = w * 32 + nt * 16 + l15;
            #pragma unroll
            for (int kb = 0; kb < 4; ++kb)
                bP[nt][kb] = *(const f16x8*)&Ks[SWZ(prow, kb * 4 + quad)];
        }
        #pragma unroll
        for (int dt = 0; dt < 8; ++dt)
            #pragma unroll
            for (int kb = 0; kb < 4; ++kb) {
                f16x8 aV = *(const f16x8*)&Vs[SWZ(dt * 16 + l15, kb * 4 + quad)];
                accO[0][dt] = mfma16(aV, bP[0][kb], accO[0][dt]);
                accO[1][dt] = mfma16(aV, bP[1][kb], accO[1][dt]);
            }
    }

    // final l over quads; store normalized partials + stats
    #pragma unroll
    for (int nt = 0; nt < 2; ++nt) {
        float lf = l_part[nt];
        lf += __shfl_xor(lf, 16);
        lf += __shfl_xor(lf, 32);
        const float inv = 1.0f / lf;
        const size_t orow =
            (((size_t)z * 4 + b) * NTOT + i0 + w * 32 + nt * 16 + l15) * CDIM;
        #pragma unroll
        for (int dt = 0; dt < 8; ++dt) {
            ushort4 u;
            u.x = f2h(accO[nt][dt][0] * inv); u.y = f2h(accO[nt][dt][1] * inv);
            u.z = f2h(accO[nt][dt][2] * inv); u.w = f2h(accO[nt][dt][3] * inv);
            *(ushort4*)&Op[orow + dt * 16 + quad * 4] = u;
        }
        if (quad == 0) {
            const int idx = (z * 4 + b) * NTOT + i0 + w * 32 + nt * 16 + l15;
            Ms[idx] = m_run[nt];
            Ls[idx] = lf;
        }
    }
}

// ---------------------------------------------------------------------------
// Output projection + residual with FUSED split-K combine.
// Op: [4][b][n][128] fp16 partials (self-normalized), Ms/Ls: [4][b*n] stats.
// out[b][o][n] = Wo·(merge(Op))^T + bo + x. grid (64, 4, 2 o-halves).
// ---------------------------------------------------------------------------
__global__ __launch_bounds__(256) void out_proj_kernel(
    const unsigned short* __restrict__ Op,
    const float* __restrict__ Ms, const float* __restrict__ Ls,
    const float* __restrict__ Wo, const float* __restrict__ bo,
    const float* __restrict__ x, float* __restrict__ out)
{
    __shared__ __align__(16) unsigned short As[64][136];  // [n][c] merged
    __shared__ __align__(16) unsigned short Ws[64][136];  // [o-half][c]

    const int t = threadIdx.x, b = blockIdx.y, n0 = blockIdx.x * 64;
    const int zo = blockIdx.z * 64;
    const int w = t >> 6, quad = (t >> 4) & 3, l15 = t & 15;

    const size_t PER = (size_t)NTOT * 4 * CDIM;   // elements per key-quarter

    #pragma unroll
    for (int r = 0; r < 4; ++r) {   // stage merged ao tile
        int flat = r * 256 + t;
        int row = flat >> 4, c16 = (flat & 15) * 8;
        const int bn = b * NTOT + n0 + row;
        float m0 = Ms[bn], m1 = Ms[bn + 16384], m2 = Ms[bn + 32768], m3 = Ms[bn + 49152];
        float M = fmaxf(fmaxf(m0, m1), fmaxf(m2, m3));
        float w0 = Ls[bn]         * __expf(m0 - M);
        float w1 = Ls[bn + 16384] * __expf(m1 - M);
        float w2 = Ls[bn + 32768] * __expf(m2 - M);
        float w3 = Ls[bn + 49152] * __expf(m3 - M);
        const float inv = 1.0f / (w0 + w1 + w2 + w3);
        w0 *= inv; w1 *= inv; w2 *= inv; w3 *= inv;

        const size_t base = (size_t)bn * CDIM + c16;
        uint4 a0 = *(const uint4*)&Op[base];
        uint4 a1 = *(const uint4*)&Op[PER + base];
        uint4 a2 = *(const uint4*)&Op[2 * PER + base];
        uint4 a3 = *(const uint4*)&Op[3 * PER + base];
        const unsigned short* p0 = (const unsigned short*)&a0;
        const unsigned short* p1 = (const unsigned short*)&a1;
        const unsigned short* p2 = (const unsigned short*)&a2;
        const unsigned short* p3 = (const unsigned short*)&a3;
        unsigned short mv[8];
        #pragma unroll
        for (int j = 0; j < 8; ++j)
            mv[j] = f2h(w0 * h2f(p0[j]) + w1 * h2f(p1[j]) +
                        w2 * h2f(p2[j]) + w3 * h2f(p3[j]));
        *(uint4*)&As[row][c16] = *(const uint4*)mv;
    }
    {
        int o = t >> 2, ch = (t & 3) * 32;
        #pragma unroll
        for (int i = 0; i < 8; ++i) {
            float4 f4 = *(const float4*)&Wo[(size_t)(zo + o) * CDIM + ch + i * 4];
            ushort4 u = { f2h(f4.x), f2h(f4.y), f2h(f4.z), f2h(f4.w) };
            *(ushort4*)&Ws[o][ch + i * 4] = u;
        }
    }
    __syncthreads();

    f16x8 bA[4];
    #pragma unroll
    for (int f = 0; f < 4; ++f)
        bA[f] = *(const f16x8*)&As[w * 16 + l15][f * 32 + quad * 8];

    #pragma unroll
    for (int ot = 0; ot < 4; ++ot) {
        floatx4 acc = (floatx4){0.f, 0.f, 0.f, 0.f};
        #pragma unroll
        for (int f = 0; f < 4; ++f) {
            f16x8 aW = *(const f16x8*)&Ws[ot * 16 + l15][f * 32 + quad * 8];
            acc = mfma16(aW, bA[f], acc);
        }
        const int ob = zo + ot * 16 + quad * 4;
        #pragma unroll
        for (int r = 0; r < 4; ++r) {
            size_t idx = ((size_t)b * CDIM + ob + r) * NTOT + n0 + w * 16 + l15;
            out[idx] = acc[r] + bo[ob + r] + x[idx];
        }
    }
}

// ---------------------------------------------------------------------------
extern "C" void kernel_launch(void* const* d_in, const int* in_sizes, int n_in,
                              void* d_out, int out_size, void* d_ws, size_t ws_size,
                              hipStream_t stream)
{
    const float* x  = (const float*)d_in[0];
    const float* Wq = (const float*)d_in[1];
    const float* bq = (const float*)d_in[2];
    const float* Wk = (const float*)d_in[3];
    const float* bk = (const float*)d_in[4];
    const float* Wv = (const float*)d_in[5];
    const float* bv = (const float*)d_in[6];
    const float* Wo = (const float*)d_in[7];
    const float* bo = (const float*)d_in[8];
    float* out = (float*)d_out;

    const size_t PER = (size_t)4 * CDIM * NTOT;   // 2,097,152 elements
    unsigned short* q_ws  = (unsigned short*)d_ws;
    unsigned short* k_ws  = q_ws + PER;
    unsigned short* v_ws  = k_ws + PER;
    unsigned short* op_ws = v_ws + PER;           // fp16 [4][b][n][c] partials
    float*          ms_ws = (float*)(op_ws + 4 * PER);   // [4][b*n]
    float*          ls_ws = ms_ws + 4 * 16384;

    qkv_proj_kernel<<<dim3(64, 4, 2), dim3(256), 0, stream>>>(
        x, Wq, bq, Wk, bk, Wv, bv, q_ws, k_ws, v_ws);
    attn_kernel<<<dim3(32, 4, 4), dim3(256), 0, stream>>>(
        q_ws, k_ws, v_ws, op_ws, ms_ws, ls_ws);
    out_proj_kernel<<<dim3(64, 4, 2), dim3(256), 0, stream>>>(
        op_ws, ms_ws, ls_ws, Wo, bo, x, out);
}